// Round 6
// baseline (294.451 us; speedup 1.0000x reference)
//
#include <hip/hip_runtime.h>
#include <hip/hip_bf16.h>

// B=4, S=2048, D=1024, H=16, DEPTH=64. Causal MHA, fp32 in/out, bf16 MFMA.

typedef __attribute__((ext_vector_type(8))) short bf16x8;
typedef __attribute__((ext_vector_type(4))) float f32x4;
typedef __attribute__((ext_vector_type(8))) unsigned short u16x8;

#define MFMA16(a, b, c) __builtin_amdgcn_mfma_f32_16x16x32_bf16(a, b, c, 0, 0, 0)

#define GLOAD_LDS16(gp, lp)                                                    \
  __builtin_amdgcn_global_load_lds(                                            \
      (const __attribute__((address_space(1))) void*)(gp),                     \
      (__attribute__((address_space(3))) void*)(lp), 16, 0, 0)

__device__ __forceinline__ unsigned short f2bf(float f) {
  union { float f; unsigned u; } x; x.f = f;
  unsigned u = x.u;
  return (unsigned short)((u + 0x7fffu + ((u >> 16) & 1u)) >> 16);
}

__device__ __forceinline__ unsigned pk2(float a, float b) {
  union { __hip_bfloat162 h; unsigned u; } cv;
  cv.h = __float22bfloat162_rn(float2{a, b});
  return cv.u;
}

// ---------------------------------------------------------------------------
// fp32 -> bf16 convert for q,k,v (3x8M) + weights (4x1M); packs qkv biases.
// ---------------------------------------------------------------------------
__global__ __launch_bounds__(256) void convert_kernel(
    const float* __restrict__ q, const float* __restrict__ k,
    const float* __restrict__ v, const float* __restrict__ wq,
    const float* __restrict__ wk, const float* __restrict__ wv,
    const float* __restrict__ wd, const float* __restrict__ bq,
    const float* __restrict__ bk, const float* __restrict__ bv,
    unsigned short* __restrict__ dst, float* __restrict__ bias_pack) {
  const size_t tid0 = (size_t)blockIdx.x * blockDim.x + threadIdx.x;
  const size_t nthreads = (size_t)gridDim.x * blockDim.x;
  if (tid0 < 3072) {
    bias_pack[tid0] = tid0 < 1024 ? bq[tid0]
                     : (tid0 < 2048 ? bk[tid0 - 1024] : bv[tid0 - 2048]);
  }
  const size_t NQ = 8192ull * 1024;
  const size_t NW = 1024ull * 1024;
  const size_t total_chunks = (3 * NQ + 4 * NW) / 8;
  for (size_t c = tid0; c < total_chunks; c += nthreads) {
    const size_t e = c * 8;
    const float* src;
    if (e < NQ) src = q + e;
    else if (e < 2 * NQ) src = k + (e - NQ);
    else if (e < 3 * NQ) src = v + (e - 2 * NQ);
    else {
      const size_t we = e - 3 * NQ;
      if (we < NW) src = wq + we;
      else if (we < 2 * NW) src = wk + (we - NW);
      else if (we < 3 * NW) src = wv + (we - 2 * NW);
      else src = wd + (we - 3 * NW);
    }
    f32x4 a = *(const f32x4*)(src);
    f32x4 b = *(const f32x4*)(src + 4);
    u16x8 o;
    o[0] = f2bf(a[0]); o[1] = f2bf(a[1]); o[2] = f2bf(a[2]); o[3] = f2bf(a[3]);
    o[4] = f2bf(b[0]); o[5] = f2bf(b[1]); o[6] = f2bf(b[2]); o[7] = f2bf(b[3]);
    *(u16x8*)(dst + e) = o;
  }
}

// ---------------------------------------------------------------------------
// GEMM: C = A[.,K=1024] @ W[.,K]^T + bias, 128x128 tile, BK=32, 4 waves.
// MODE 0 (QKV fused, z=0..2):
//   z=0: Q -> head layout (B,H,S,64), scaled by 1/sqrt(64)*log2(e)
//   z=1: K -> head layout
//   z=2: V^T -> (B,H,64,S), k pi-permuted per 64-token tile; roles swapped
// MODE 1: dense projection, fp32 row-major out.
// ---------------------------------------------------------------------------
template <int MODE>
__global__ __launch_bounds__(256) void gemm_kernel(
    const unsigned short* __restrict__ Abase,
    const unsigned short* __restrict__ Wbase,
    const float* __restrict__ biasbase, unsigned short* __restrict__ dstb,
    float* __restrict__ dstf) {
  __shared__ __attribute__((aligned(16))) unsigned short Ablk[128 * 32];
  __shared__ __attribute__((aligned(16))) unsigned short Bblk[128 * 32];
  const size_t NQ = 8192ull * 1024, NW = 1024ull * 1024;
  const int z = blockIdx.z;
  const unsigned short* A;
  const unsigned short* W;
  int m0, n0;
  if (MODE == 0 && z == 2) {
    A = Wbase + 2 * NW;      // W_v  [1024 x 1024]
    W = Abase + 2 * NQ;      // v activations [8192 x 1024]
    m0 = blockIdx.x * 128;   // feature tiles (8)
    n0 = blockIdx.y * 128;   // token tiles (64)
  } else {
    A = Abase + (size_t)z * NQ;
    W = Wbase + (size_t)z * NW;
    m0 = blockIdx.y * 128;
    n0 = blockIdx.x * 128;
  }
  const float* bias = biasbase + (size_t)z * 1024;
  const int tid = threadIdx.x, lane = tid & 63, w = tid >> 6;
  const int wr = (w >> 1) * 64, wc = (w & 1) * 64;
  const int llo = lane & 15, lhi = lane >> 4;
  f32x4 acc[4][4] = {};
  const unsigned short* ag = A + (size_t)(m0 + (tid >> 2)) * 1024 + (tid & 3) * 8;
  const unsigned short* wg = W + (size_t)(n0 + (tid >> 2)) * 1024 + (tid & 3) * 8;
  unsigned short* lA = &Ablk[tid * 8];
  unsigned short* lA2 = &Ablk[2048 + tid * 8];
  unsigned short* lB = &Bblk[tid * 8];
  unsigned short* lB2 = &Bblk[2048 + tid * 8];
  for (int kt = 0; kt < 32; ++kt) {
    const int ko = kt * 32;
    if (kt) __syncthreads();
    GLOAD_LDS16(ag + ko, lA);
    GLOAD_LDS16(ag + ko + 64 * 1024, lA2);
    GLOAD_LDS16(wg + ko, lB);
    GLOAD_LDS16(wg + ko + 64 * 1024, lB2);
    __syncthreads();
    bf16x8 af[4], bfr[4];
#pragma unroll
    for (int i = 0; i < 4; ++i)
      af[i] = *(const bf16x8*)&Ablk[(wr + i * 16 + llo) * 32 + lhi * 8];
#pragma unroll
    for (int i = 0; i < 4; ++i)
      bfr[i] = *(const bf16x8*)&Bblk[(wc + i * 16 + llo) * 32 + lhi * 8];
#pragma unroll
    for (int mi = 0; mi < 4; ++mi)
#pragma unroll
      for (int ni = 0; ni < 4; ++ni)
        acc[mi][ni] = MFMA16(af[mi], bfr[ni], acc[mi][ni]);
  }
  // C/D layout: col = lane&15, row = (lane>>4)*4 + r
  const float osc = (MODE == 0 && z == 0) ? 0.1803368801f : 1.0f;  // SCL for Q
#pragma unroll
  for (int mi = 0; mi < 4; ++mi) {
#pragma unroll
    for (int ni = 0; ni < 4; ++ni) {
      const int n = n0 + wc + ni * 16 + llo;
      const float bv = (MODE == 0) ? ((z == 2) ? 0.f : bias[n]) : bias[n];
#pragma unroll
      for (int r = 0; r < 4; ++r) {
        const int m = m0 + wr + mi * 16 + lhi * 4 + r;
        float val = acc[mi][ni][r] + bv;
        if (MODE == 1) {
          dstf[(size_t)m * 1024 + n] = val;
        } else if (z < 2) {
          val *= osc;
          const int b = m >> 11, s = m & 2047, h = n >> 6, d = n & 63;
          dstb[(size_t)z * NQ +
               (((size_t)(b * 16 + h) * 2048 + s) * 64 + d)] = f2bf(val);
        } else {  // z==2: m = feature (h*64+d), n = token (b*2048+s)
          val = acc[mi][ni][r] + bias[m];
          const int h = m >> 6, d = m & 63, b = n >> 11, sidx = n & 2047;
          const int t = sidx & 63;
          const int ps = (sidx & ~63) | ((t & 15) << 2) | (t >> 4);  // pi(t)
          dstb[2 * NQ + (((size_t)(b * 16 + h) * 64 + d) * 2048 + ps)] = f2bf(val);
        }
      }
    }
  }
}

// ---------------------------------------------------------------------------
// Causal flash attention, barrier-free. Grid: (B*H, S/128). Block: 256 = 4
// waves, wave w owns 32 q-rows. KV tile = 64, K/V^T read DIRECTLY from global
// (L2-resident: 512KB/head, shared by 16 blocks) — no LDS staging, no
// __syncthreads in the K-loop; each wave walks only its causal tile range.
// No online max (Q pre-scaled to log2 domain). l via ones-fragment MFMA.
// P stored k-pi-permuted in wave-local LDS (matches V^T pi layout).
// ---------------------------------------------------------------------------
__global__ __launch_bounds__(256, 4) void attn_kernel(
    const unsigned short* __restrict__ Qp, const unsigned short* __restrict__ Kp,
    const unsigned short* __restrict__ Vtp, unsigned short* __restrict__ attn_out) {
  __shared__ __attribute__((aligned(16))) unsigned short Plds[4 * 32 * 72];
  const int bh = blockIdx.x;
  const int qt = 15 - blockIdx.y;  // biggest q-tiles dispatch first
  const int tid = threadIdx.x, lane = tid & 63, w = tid >> 6;
  const int llo = lane & 15, lhi = lane >> 4;
  const int qbase = qt * 128 + w * 32;

  // Q fragments (pre-scaled to log2 domain): rows qbase+mi*16+llo
  bf16x8 qf[2][2];
#pragma unroll
  for (int mi = 0; mi < 2; ++mi) {
    const unsigned short* qptr =
        Qp + ((size_t)bh * 2048 + qbase + mi * 16 + llo) * 64 + lhi * 8;
    qf[mi][0] = *(const bf16x8*)qptr;
    qf[mi][1] = *(const bf16x8*)(qptr + 32);
  }

  bf16x8 ones;
#pragma unroll
  for (int i = 0; i < 8; ++i) ones[i] = (short)0x3F80;

  f32x4 o[2][5] = {};  // [mi][dblk]; dblk 4 = l (row-sum)

  const size_t kbase = (size_t)bh * (64 * 2048);
  const unsigned short* kfrag = Kp + kbase + (size_t)llo * 64 + lhi * 8;
  const unsigned short* vfrag = Vtp + kbase + (size_t)llo * 2048 + lhi * 8;
  unsigned short* pw = &Plds[w * (32 * 72)];

  const int nkt = (qbase + 31) / 64 + 1;  // causal: tiles with kv0 <= qbase+31
  for (int kt = 0; kt < nkt; ++kt) {
    const int kv0 = kt * 64;

    // ---- S = Q K^T, K fragments straight from global (L2)
    f32x4 s[2][4] = {};
    __builtin_amdgcn_s_setprio(1);
#pragma unroll
    for (int b4 = 0; b4 < 4; ++b4) {
      const unsigned short* kp = kfrag + (size_t)(kv0 + b4 * 16) * 64;
      const bf16x8 k0 = *(const bf16x8*)kp;
      const bf16x8 k1 = *(const bf16x8*)(kp + 32);
      s[0][b4] = MFMA16(qf[0][0], k0, s[0][b4]);
      s[0][b4] = MFMA16(qf[0][1], k1, s[0][b4]);
      s[1][b4] = MFMA16(qf[1][0], k0, s[1][b4]);
      s[1][b4] = MFMA16(qf[1][1], k1, s[1][b4]);
    }
    __builtin_amdgcn_s_setprio(0);

    // ---- P = exp2(S) (+causal mask on diagonal tiles), packed pi-store
    const bool needm = (kv0 + 63 > qbase);
#pragma unroll
    for (int mi = 0; mi < 2; ++mi) {
#pragma unroll
      for (int r = 0; r < 4; ++r) {
        float sv0 = s[mi][0][r], sv1 = s[mi][1][r];
        float sv2 = s[mi][2][r], sv3 = s[mi][3][r];
        if (needm) {
          const int qrow = qbase + mi * 16 + lhi * 4 + r;
          if (kv0 + llo > qrow) sv0 = -1e9f;
          if (kv0 + 16 + llo > qrow) sv1 = -1e9f;
          if (kv0 + 32 + llo > qrow) sv2 = -1e9f;
          if (kv0 + 48 + llo > qrow) sv3 = -1e9f;
        }
        const float p0 = exp2f(sv0), p1 = exp2f(sv1);
        const float p2 = exp2f(sv2), p3 = exp2f(sv3);
        const int prow = mi * 16 + lhi * 4 + r;
        *(uint2*)&pw[prow * 72 + llo * 4] = make_uint2(pk2(p0, p1), pk2(p2, p3));
      }
    }

    // ---- O += P V^T, V fragments straight from global (L2); l via ones
    bf16x8 pa[2][2];
#pragma unroll
    for (int mi = 0; mi < 2; ++mi) {
      pa[mi][0] = *(const bf16x8*)&pw[(mi * 16 + llo) * 72 + lhi * 8];
      pa[mi][1] = *(const bf16x8*)&pw[(mi * 16 + llo) * 72 + 32 + lhi * 8];
    }
    __builtin_amdgcn_s_setprio(1);
#pragma unroll
    for (int dblk = 0; dblk < 4; ++dblk) {
      const unsigned short* vp = vfrag + (size_t)(dblk * 16) * 2048 + kv0;
      const bf16x8 v0 = *(const bf16x8*)vp;
      const bf16x8 v1 = *(const bf16x8*)(vp + 32);
      o[0][dblk] = MFMA16(pa[0][0], v0, o[0][dblk]);
      o[0][dblk] = MFMA16(pa[0][1], v1, o[0][dblk]);
      o[1][dblk] = MFMA16(pa[1][0], v0, o[1][dblk]);
      o[1][dblk] = MFMA16(pa[1][1], v1, o[1][dblk]);
    }
    o[0][4] = MFMA16(pa[0][0], ones, o[0][4]);
    o[0][4] = MFMA16(pa[0][1], ones, o[0][4]);
    o[1][4] = MFMA16(pa[1][0], ones, o[1][4]);
    o[1][4] = MFMA16(pa[1][1], ones, o[1][4]);
    __builtin_amdgcn_s_setprio(0);
  }

  // ---- epilogue: O/l, scatter to (B,S,D) bf16. l is in every lane's o[mi][4].
  const int b = bh >> 4, h = bh & 15;
#pragma unroll
  for (int mi = 0; mi < 2; ++mi) {
#pragma unroll
    for (int r = 0; r < 4; ++r) {
      const float inv = 1.0f / o[mi][4][r];
      const int qrow = qbase + mi * 16 + lhi * 4 + r;
      const size_t base = ((size_t)b * 2048 + qrow) * 1024 + h * 64;
#pragma unroll
      for (int dblk = 0; dblk < 4; ++dblk)
        attn_out[base + dblk * 16 + llo] = f2bf(o[mi][dblk][r] * inv);
    }
  }
}

// ---------------------------------------------------------------------------
extern "C" void kernel_launch(void* const* d_in, const int* in_sizes, int n_in,
                              void* d_out, int out_size, void* d_ws,
                              size_t ws_size, hipStream_t stream) {
  const float* q = (const float*)d_in[0];
  const float* k = (const float*)d_in[1];
  const float* v = (const float*)d_in[2];
  const float* wq_w = (const float*)d_in[3];
  const float* wq_b = (const float*)d_in[4];
  const float* wk_w = (const float*)d_in[5];
  const float* wk_b = (const float*)d_in[6];
  const float* wv_w = (const float*)d_in[7];
  const float* wv_b = (const float*)d_in[8];
  const float* dense_w = (const float*)d_in[9];
  const float* dense_b = (const float*)d_in[10];
  float* out = (float*)d_out;

  char* ws = (char*)d_ws;
  const size_t MB = 1024ull * 1024;
  unsigned short* qkv_bf = (unsigned short*)(ws);
  unsigned short* w_bf = (unsigned short*)(ws + 48 * MB);
  float* bias_pack = (float*)(ws + 56 * MB);
  unsigned short* qkvp = (unsigned short*)(ws + 57 * MB);
  unsigned short* attn_o = (unsigned short*)(ws + 105 * MB);
  const size_t PEL = 8192ull * 1024;

  convert_kernel<<<dim3(2048), dim3(256), 0, stream>>>(
      q, k, v, wq_w, wk_w, wv_w, dense_w, wq_b, wk_b, wv_b, qkv_bf, bias_pack);

  // Q (scaled), K -> (B,H,S,64); V^T pi-permuted -> (B,H,64,S). One dispatch.
  gemm_kernel<0><<<dim3(8, 64, 3), dim3(256), 0, stream>>>(
      qkv_bf, w_bf, bias_pack, qkvp, nullptr);

  attn_kernel<<<dim3(64, 16), dim3(256), 0, stream>>>(
      qkvp, qkvp + PEL, qkvp + 2 * PEL, attn_o);

  gemm_kernel<1><<<dim3(8, 64, 1), dim3(256), 0, stream>>>(
      attn_o, w_bf + 3ull * 1024 * 1024, dense_b, nullptr, out);
}

// Round 7
// 233.255 us; speedup vs baseline: 1.2624x; 1.2624x over previous
//
#include <hip/hip_runtime.h>
#include <hip/hip_bf16.h>

// B=4, S=2048, D=1024, H=16, DEPTH=64. Causal MHA, fp32 in/out, bf16 MFMA.

typedef __attribute__((ext_vector_type(8))) short bf16x8;
typedef __attribute__((ext_vector_type(4))) float f32x4;
typedef __attribute__((ext_vector_type(8))) unsigned short u16x8;

#define MFMA16(a, b, c) __builtin_amdgcn_mfma_f32_16x16x32_bf16(a, b, c, 0, 0, 0)

#define GLOAD_LDS16(gp, lp)                                                    \
  __builtin_amdgcn_global_load_lds(                                            \
      (const __attribute__((address_space(1))) void*)(gp),                     \
      (__attribute__((address_space(3))) void*)(lp), 16, 0, 0)

__device__ __forceinline__ unsigned short f2bf(float f) {
  union { float f; unsigned u; } x; x.f = f;
  unsigned u = x.u;
  return (unsigned short)((u + 0x7fffu + ((u >> 16) & 1u)) >> 16);
}

__device__ __forceinline__ unsigned pk2(float a, float b) {
  union { __hip_bfloat162 h; unsigned u; } cv;
  cv.h = __float22bfloat162_rn(float2{a, b});
  return cv.u;
}

// ---------------------------------------------------------------------------
// fp32 -> bf16 convert for q,k,v (3x8M) + weights (4x1M); packs qkv biases.
// ---------------------------------------------------------------------------
__global__ __launch_bounds__(256) void convert_kernel(
    const float* __restrict__ q, const float* __restrict__ k,
    const float* __restrict__ v, const float* __restrict__ wq,
    const float* __restrict__ wk, const float* __restrict__ wv,
    const float* __restrict__ wd, const float* __restrict__ bq,
    const float* __restrict__ bk, const float* __restrict__ bv,
    unsigned short* __restrict__ dst, float* __restrict__ bias_pack) {
  const size_t tid0 = (size_t)blockIdx.x * blockDim.x + threadIdx.x;
  const size_t nthreads = (size_t)gridDim.x * blockDim.x;
  if (tid0 < 3072) {
    bias_pack[tid0] = tid0 < 1024 ? bq[tid0]
                     : (tid0 < 2048 ? bk[tid0 - 1024] : bv[tid0 - 2048]);
  }
  const size_t NQ = 8192ull * 1024;
  const size_t NW = 1024ull * 1024;
  const size_t total_chunks = (3 * NQ + 4 * NW) / 8;
  for (size_t c = tid0; c < total_chunks; c += nthreads) {
    const size_t e = c * 8;
    const float* src;
    if (e < NQ) src = q + e;
    else if (e < 2 * NQ) src = k + (e - NQ);
    else if (e < 3 * NQ) src = v + (e - 2 * NQ);
    else {
      const size_t we = e - 3 * NQ;
      if (we < NW) src = wq + we;
      else if (we < 2 * NW) src = wk + (we - NW);
      else if (we < 3 * NW) src = wv + (we - 2 * NW);
      else src = wd + (we - 3 * NW);
    }
    f32x4 a = *(const f32x4*)(src);
    f32x4 b = *(const f32x4*)(src + 4);
    u16x8 o;
    o[0] = f2bf(a[0]); o[1] = f2bf(a[1]); o[2] = f2bf(a[2]); o[3] = f2bf(a[3]);
    o[4] = f2bf(b[0]); o[5] = f2bf(b[1]); o[6] = f2bf(b[2]); o[7] = f2bf(b[3]);
    *(u16x8*)(dst + e) = o;
  }
}

// ---------------------------------------------------------------------------
// GEMM: C = A[.,K=1024] @ W[.,K]^T + bias, 128x128 tile, BK=32, 4 waves.
// XCD-chunked blockIdx swizzle: consecutive blocks sharing an A-panel land
// on the same XCD's L2.
// MODE 0 (QKV fused, z=0..2):
//   z=0: Q -> head layout (B,H,S,64), scaled by 1/sqrt(64)*log2(e)
//   z=1: K -> head layout
//   z=2: V^T -> (B,H,64,S), k pi-permuted per 64-token tile; roles swapped
// MODE 1: dense projection, fp32 row-major out.
// ---------------------------------------------------------------------------
template <int MODE>
__global__ __launch_bounds__(256) void gemm_kernel(
    const unsigned short* __restrict__ Abase,
    const unsigned short* __restrict__ Wbase,
    const float* __restrict__ biasbase, unsigned short* __restrict__ dstb,
    float* __restrict__ dstf) {
  __shared__ __attribute__((aligned(16))) unsigned short Ablk[128 * 32];
  __shared__ __attribute__((aligned(16))) unsigned short Bblk[128 * 32];
  const size_t NQ = 8192ull * 1024, NW = 1024ull * 1024;
  // XCD swizzle (grid is (8,64,gz), nwg % 8 == 0)
  int flat = ((int)blockIdx.z * 64 + blockIdx.y) * 8 + blockIdx.x;
  const int cpx = (gridDim.x * gridDim.y * gridDim.z) >> 3;
  flat = (flat & 7) * cpx + (flat >> 3);
  const int bz = flat >> 9;
  const int rem = flat & 511;
  const int by = rem >> 3, bx = rem & 7;

  const int z = bz;
  const unsigned short* A;
  const unsigned short* W;
  int m0, n0;
  if (MODE == 0 && z == 2) {
    A = Wbase + 2 * NW;      // W_v  [1024 x 1024]
    W = Abase + 2 * NQ;      // v activations [8192 x 1024]
    m0 = bx * 128;           // feature tiles (8)
    n0 = by * 128;           // token tiles (64)
  } else {
    A = Abase + (size_t)z * NQ;
    W = Wbase + (size_t)z * NW;
    m0 = by * 128;
    n0 = bx * 128;
  }
  const float* bias = biasbase + (size_t)z * 1024;
  const int tid = threadIdx.x, lane = tid & 63, w = tid >> 6;
  const int wr = (w >> 1) * 64, wc = (w & 1) * 64;
  const int llo = lane & 15, lhi = lane >> 4;
  f32x4 acc[4][4] = {};
  const unsigned short* ag = A + (size_t)(m0 + (tid >> 2)) * 1024 + (tid & 3) * 8;
  const unsigned short* wg = W + (size_t)(n0 + (tid >> 2)) * 1024 + (tid & 3) * 8;
  unsigned short* lA = &Ablk[tid * 8];
  unsigned short* lA2 = &Ablk[2048 + tid * 8];
  unsigned short* lB = &Bblk[tid * 8];
  unsigned short* lB2 = &Bblk[2048 + tid * 8];
  for (int kt = 0; kt < 32; ++kt) {
    const int ko = kt * 32;
    if (kt) __syncthreads();
    GLOAD_LDS16(ag + ko, lA);
    GLOAD_LDS16(ag + ko + 64 * 1024, lA2);
    GLOAD_LDS16(wg + ko, lB);
    GLOAD_LDS16(wg + ko + 64 * 1024, lB2);
    __syncthreads();
    bf16x8 af[4], bfr[4];
#pragma unroll
    for (int i = 0; i < 4; ++i)
      af[i] = *(const bf16x8*)&Ablk[(wr + i * 16 + llo) * 32 + lhi * 8];
#pragma unroll
    for (int i = 0; i < 4; ++i)
      bfr[i] = *(const bf16x8*)&Bblk[(wc + i * 16 + llo) * 32 + lhi * 8];
#pragma unroll
    for (int mi = 0; mi < 4; ++mi)
#pragma unroll
      for (int ni = 0; ni < 4; ++ni)
        acc[mi][ni] = MFMA16(af[mi], bfr[ni], acc[mi][ni]);
  }
  // C/D layout: col = lane&15, row = (lane>>4)*4 + r
  const float osc = (MODE == 0 && z == 0) ? 0.1803368801f : 1.0f;  // SCL for Q
#pragma unroll
  for (int mi = 0; mi < 4; ++mi) {
#pragma unroll
    for (int ni = 0; ni < 4; ++ni) {
      const int n = n0 + wc + ni * 16 + llo;
      const float bv = (MODE == 0) ? ((z == 2) ? 0.f : bias[n]) : bias[n];
#pragma unroll
      for (int r = 0; r < 4; ++r) {
        const int m = m0 + wr + mi * 16 + lhi * 4 + r;
        float val = acc[mi][ni][r] + bv;
        if (MODE == 1) {
          dstf[(size_t)m * 1024 + n] = val;
        } else if (z < 2) {
          val *= osc;
          const int b = m >> 11, s = m & 2047, h = n >> 6, d = n & 63;
          dstb[(size_t)z * NQ +
               (((size_t)(b * 16 + h) * 2048 + s) * 64 + d)] = f2bf(val);
        } else {  // z==2: m = feature (h*64+d), n = token (b*2048+s)
          val = acc[mi][ni][r] + bias[m];
          const int h = m >> 6, d = m & 63, b = n >> 11, sidx = n & 2047;
          const int t = sidx & 63;
          const int ps = (sidx & ~63) | ((t & 15) << 2) | (t >> 4);  // pi(t)
          dstb[2 * NQ + (((size_t)(b * 16 + h) * 64 + d) * 2048 + ps)] = f2bf(val);
        }
      }
    }
  }
}

// ---------------------------------------------------------------------------
// Causal flash attention, 2-phase double-buffered staging (R4 base).
// Grid: 1024 blocks, XCD-chunked so each XCD owns 8 heads (K/V = 4MB = L2).
// Block: 256 = 4 waves, wave owns 32 q-rows. KV tile = 64.
// Loop: STAGE(t+1) -> compute(t) -> __syncthreads (drain lands during compute).
// No online max (Q pre-scaled to log2 domain). l via ones-fragment MFMA.
// P stored k-pi-permuted in wave-local LDS (matches V^T pi layout).
// ---------------------------------------------------------------------------
__global__ __launch_bounds__(256, 3) void attn_kernel(
    const unsigned short* __restrict__ Qp, const unsigned short* __restrict__ Kp,
    const unsigned short* __restrict__ Vtp, unsigned short* __restrict__ attn_out) {
  __shared__ __attribute__((aligned(16))) unsigned short Klds[2][64 * 64];  // swz
  __shared__ __attribute__((aligned(16))) unsigned short Vt[2][64 * 64];    // swz
  __shared__ __attribute__((aligned(16))) unsigned short Plds[4 * 32 * 72];
  // XCD swizzle: flat in [0,1024); xcd gets 128 consecutive = 8 bh x 16 qsel
  int flat = (int)blockIdx.y * 64 + blockIdx.x;
  flat = (flat & 7) * 128 + (flat >> 3);
  const int bh = flat >> 4;
  const int qt = 15 - (flat & 15);  // biggest q-tiles first within chunk
  const int tid = threadIdx.x, lane = tid & 63, w = tid >> 6;
  const int llo = lane & 15, lhi = lane >> 4;
  const int qbase = qt * 128 + w * 32;

  // Q fragments (pre-scaled to log2 domain): rows qbase+mi*16+llo
  bf16x8 qf[2][2];
#pragma unroll
  for (int mi = 0; mi < 2; ++mi) {
    const unsigned short* qptr =
        Qp + ((size_t)bh * 2048 + qbase + mi * 16 + llo) * 64 + lhi * 8;
    qf[mi][0] = *(const bf16x8*)qptr;
    qf[mi][1] = *(const bf16x8*)(qptr + 32);
  }

  bf16x8 ones;
#pragma unroll
  for (int i = 0; i < 8; ++i) ones[i] = (short)0x3F80;

  f32x4 o[2][5] = {};  // [mi][dblk]; dblk 4 = l (row-sum)

  const size_t kbase = (size_t)bh * (64 * 2048);
  const int r0 = tid >> 3, r1 = r0 + 32;
  const int scb = (tid & 7) * 16;
  const int kcol0 = (scb ^ ((r0 & 7) << 4)) >> 1;
  const int kcol1 = (scb ^ ((r1 & 7) << 4)) >> 1;
  const int koff0 = r0 * 64 + kcol0, koff1 = r1 * 64 + kcol1;
  const int voff0 = r0 * 2048 + kcol0, voff1 = r1 * 2048 + kcol1;
  unsigned short* pw = &Plds[w * (32 * 72)];

  const int nkt = 2 * (qt + 1);

#define STAGE(buf, kv0_)                                                       \
  do {                                                                         \
    GLOAD_LDS16(Kp + kbase + (size_t)(kv0_)*64 + koff0, &Klds[buf][tid * 8]);  \
    GLOAD_LDS16(Kp + kbase + (size_t)(kv0_)*64 + koff1,                        \
                &Klds[buf][2048 + tid * 8]);                                   \
    GLOAD_LDS16(Vtp + kbase + (kv0_) + voff0, &Vt[buf][tid * 8]);              \
    GLOAD_LDS16(Vtp + kbase + (kv0_) + voff1, &Vt[buf][2048 + tid * 8]);       \
  } while (0)

  STAGE(0, 0);
  __syncthreads();

  for (int kt = 0; kt < nkt; ++kt) {
    const int kv0 = kt * 64;
    const int cb = kt & 1;
    if (kt + 1 < nkt) STAGE(cb ^ 1, kv0 + 64);

    if (kv0 <= qbase + 31) {  // wave-uniform causal skip
      // ---- S = Q K^T
      f32x4 s[2][4] = {};
      __builtin_amdgcn_s_setprio(1);
#pragma unroll
      for (int b4 = 0; b4 < 4; ++b4) {
        const int row = b4 * 16 + llo;
        const int sw = (row & 7) << 3;
        const bf16x8 k0 = *(const bf16x8*)&Klds[cb][row * 64 + ((lhi * 8) ^ sw)];
        const bf16x8 k1 =
            *(const bf16x8*)&Klds[cb][row * 64 + ((32 + lhi * 8) ^ sw)];
        s[0][b4] = MFMA16(qf[0][0], k0, s[0][b4]);
        s[0][b4] = MFMA16(qf[0][1], k1, s[0][b4]);
        s[1][b4] = MFMA16(qf[1][0], k0, s[1][b4]);
        s[1][b4] = MFMA16(qf[1][1], k1, s[1][b4]);
      }
      __builtin_amdgcn_s_setprio(0);

      // ---- P = exp2(S) (+causal mask on diagonal tiles), packed pi-store
      const bool needm = (kv0 + 63 > qbase);
#pragma unroll
      for (int mi = 0; mi < 2; ++mi) {
#pragma unroll
        for (int r = 0; r < 4; ++r) {
          float sv0 = s[mi][0][r], sv1 = s[mi][1][r];
          float sv2 = s[mi][2][r], sv3 = s[mi][3][r];
          if (needm) {
            const int qrow = qbase + mi * 16 + lhi * 4 + r;
            if (kv0 + llo > qrow) sv0 = -1e9f;
            if (kv0 + 16 + llo > qrow) sv1 = -1e9f;
            if (kv0 + 32 + llo > qrow) sv2 = -1e9f;
            if (kv0 + 48 + llo > qrow) sv3 = -1e9f;
          }
          const float p0 = exp2f(sv0), p1 = exp2f(sv1);
          const float p2 = exp2f(sv2), p3 = exp2f(sv3);
          const int prow = mi * 16 + lhi * 4 + r;
          *(uint2*)&pw[prow * 72 + llo * 4] =
              make_uint2(pk2(p0, p1), pk2(p2, p3));
        }
      }

      // ---- O += P V^T; l via ones B-fragment (lands in every lane)
      bf16x8 pa[2][2];
#pragma unroll
      for (int mi = 0; mi < 2; ++mi) {
        pa[mi][0] = *(const bf16x8*)&pw[(mi * 16 + llo) * 72 + lhi * 8];
        pa[mi][1] = *(const bf16x8*)&pw[(mi * 16 + llo) * 72 + 32 + lhi * 8];
      }
      __builtin_amdgcn_s_setprio(1);
#pragma unroll
      for (int dblk = 0; dblk < 4; ++dblk) {
        const int row = dblk * 16 + llo;
        const int sw = (row & 7) << 3;
        const bf16x8 v0 = *(const bf16x8*)&Vt[cb][row * 64 + ((lhi * 8) ^ sw)];
        const bf16x8 v1 =
            *(const bf16x8*)&Vt[cb][row * 64 + ((32 + lhi * 8) ^ sw)];
        o[0][dblk] = MFMA16(pa[0][0], v0, o[0][dblk]);
        o[0][dblk] = MFMA16(pa[0][1], v1, o[0][dblk]);
        o[1][dblk] = MFMA16(pa[1][0], v0, o[1][dblk]);
        o[1][dblk] = MFMA16(pa[1][1], v1, o[1][dblk]);
      }
      o[0][4] = MFMA16(pa[0][0], ones, o[0][4]);
      o[0][4] = MFMA16(pa[0][1], ones, o[0][4]);
      o[1][4] = MFMA16(pa[1][0], ones, o[1][4]);
      o[1][4] = MFMA16(pa[1][1], ones, o[1][4]);
      __builtin_amdgcn_s_setprio(0);
    }

    __syncthreads();  // drains vmcnt: STAGE(t+1) had full compute(t) to land
  }
#undef STAGE

  // ---- epilogue: O/l, scatter to (B,S,D) bf16
  const int b = bh >> 4, h = bh & 15;
#pragma unroll
  for (int mi = 0; mi < 2; ++mi) {
#pragma unroll
    for (int r = 0; r < 4; ++r) {
      const float inv = 1.0f / o[mi][4][r];
      const int qrow = qbase + mi * 16 + lhi * 4 + r;
      const size_t base = ((size_t)b * 2048 + qrow) * 1024 + h * 64;
#pragma unroll
      for (int dblk = 0; dblk < 4; ++dblk)
        attn_out[base + dblk * 16 + llo] = f2bf(o[mi][dblk][r] * inv);
    }
  }
}

// ---------------------------------------------------------------------------
extern "C" void kernel_launch(void* const* d_in, const int* in_sizes, int n_in,
                              void* d_out, int out_size, void* d_ws,
                              size_t ws_size, hipStream_t stream) {
  const float* q = (const float*)d_in[0];
  const float* k = (const float*)d_in[1];
  const float* v = (const float*)d_in[2];
  const float* wq_w = (const float*)d_in[3];
  const float* wq_b = (const float*)d_in[4];
  const float* wk_w = (const float*)d_in[5];
  const float* wk_b = (const float*)d_in[6];
  const float* wv_w = (const float*)d_in[7];
  const float* wv_b = (const float*)d_in[8];
  const float* dense_w = (const float*)d_in[9];
  const float* dense_b = (const float*)d_in[10];
  float* out = (float*)d_out;

  char* ws = (char*)d_ws;
  const size_t MB = 1024ull * 1024;
  unsigned short* qkv_bf = (unsigned short*)(ws);
  unsigned short* w_bf = (unsigned short*)(ws + 48 * MB);
  float* bias_pack = (float*)(ws + 56 * MB);
  unsigned short* qkvp = (unsigned short*)(ws + 57 * MB);
  unsigned short* attn_o = (unsigned short*)(ws + 105 * MB);
  const size_t PEL = 8192ull * 1024;

  convert_kernel<<<dim3(2048), dim3(256), 0, stream>>>(
      q, k, v, wq_w, wk_w, wv_w, dense_w, wq_b, wk_b, wv_b, qkv_bf, bias_pack);

  // Q (scaled), K -> (B,H,S,64); V^T pi-permuted -> (B,H,64,S). One dispatch.
  gemm_kernel<0><<<dim3(8, 64, 3), dim3(256), 0, stream>>>(
      qkv_bf, w_bf, bias_pack, qkvp, nullptr);

  attn_kernel<<<dim3(64, 16), dim3(256), 0, stream>>>(
      qkvp, qkvp + PEL, qkvp + 2 * PEL, attn_o);

  gemm_kernel<1><<<dim3(8, 64, 1), dim3(256), 0, stream>>>(
      attn_o, w_bf + 3ull * 1024 * 1024, dense_b, nullptr, out);
}

// Round 8
// 210.092 us; speedup vs baseline: 1.4015x; 1.1103x over previous
//
#include <hip/hip_runtime.h>
#include <hip/hip_bf16.h>

// B=4, S=2048, D=1024, H=16, DEPTH=64. Causal MHA, fp32 in/out, bf16 MFMA.

typedef __attribute__((ext_vector_type(8))) short bf16x8;
typedef __attribute__((ext_vector_type(4))) float f32x4;
typedef __attribute__((ext_vector_type(8))) unsigned short u16x8;

#define MFMA16(a, b, c) __builtin_amdgcn_mfma_f32_16x16x32_bf16(a, b, c, 0, 0, 0)

#define GLOAD_LDS16(gp, lp)                                                    \
  __builtin_amdgcn_global_load_lds(                                            \
      (const __attribute__((address_space(1))) void*)(gp),                     \
      (__attribute__((address_space(3))) void*)(lp), 16, 0, 0)

__device__ __forceinline__ unsigned short f2bf(float f) {
  union { float f; unsigned u; } x; x.f = f;
  unsigned u = x.u;
  return (unsigned short)((u + 0x7fffu + ((u >> 16) & 1u)) >> 16);
}

__device__ __forceinline__ unsigned pk2(float a, float b) {
  union { __hip_bfloat162 h; unsigned u; } cv;
  cv.h = __float22bfloat162_rn(float2{a, b});
  return cv.u;
}

// ---------------------------------------------------------------------------
// fp32 -> bf16 convert for q,k,v (3x8M) + weights (4x1M); packs qkv biases.
// ---------------------------------------------------------------------------
__global__ __launch_bounds__(256) void convert_kernel(
    const float* __restrict__ q, const float* __restrict__ k,
    const float* __restrict__ v, const float* __restrict__ wq,
    const float* __restrict__ wk, const float* __restrict__ wv,
    const float* __restrict__ wd, const float* __restrict__ bq,
    const float* __restrict__ bk, const float* __restrict__ bv,
    unsigned short* __restrict__ dst, float* __restrict__ bias_pack) {
  const size_t tid0 = (size_t)blockIdx.x * blockDim.x + threadIdx.x;
  const size_t nthreads = (size_t)gridDim.x * blockDim.x;
  if (tid0 < 3072) {
    bias_pack[tid0] = tid0 < 1024 ? bq[tid0]
                     : (tid0 < 2048 ? bk[tid0 - 1024] : bv[tid0 - 2048]);
  }
  const size_t NQ = 8192ull * 1024;
  const size_t NW = 1024ull * 1024;
  const size_t total_chunks = (3 * NQ + 4 * NW) / 8;
  for (size_t c = tid0; c < total_chunks; c += nthreads) {
    const size_t e = c * 8;
    const float* src;
    if (e < NQ) src = q + e;
    else if (e < 2 * NQ) src = k + (e - NQ);
    else if (e < 3 * NQ) src = v + (e - 2 * NQ);
    else {
      const size_t we = e - 3 * NQ;
      if (we < NW) src = wq + we;
      else if (we < 2 * NW) src = wk + (we - NW);
      else if (we < 3 * NW) src = wv + (we - 2 * NW);
      else src = wd + (we - 3 * NW);
    }
    f32x4 a = *(const f32x4*)(src);
    f32x4 b = *(const f32x4*)(src + 4);
    u16x8 o;
    o[0] = f2bf(a[0]); o[1] = f2bf(a[1]); o[2] = f2bf(a[2]); o[3] = f2bf(a[3]);
    o[4] = f2bf(b[0]); o[5] = f2bf(b[1]); o[6] = f2bf(b[2]); o[7] = f2bf(b[3]);
    *(u16x8*)(dst + e) = o;
  }
}

// ---------------------------------------------------------------------------
// GEMM: C = A[.,K=1024] @ W[.,K]^T + bias, 128x128 tile, BK=32, 4 waves.
// XCD-chunked blockIdx swizzle.
// MODE 0 (QKV fused, z=0..2):
//   z=0: Q -> head layout (B,H,S,64), scaled by 1/sqrt(64)*log2(e)
//   z=1: K -> head layout
//   z=2: V^T -> (B,H,64,S), k pi-permuted per 64-token tile; roles swapped
// MODE 1: dense projection, fp32 row-major out.
// ---------------------------------------------------------------------------
template <int MODE>
__global__ __launch_bounds__(256) void gemm_kernel(
    const unsigned short* __restrict__ Abase,
    const unsigned short* __restrict__ Wbase,
    const float* __restrict__ biasbase, unsigned short* __restrict__ dstb,
    float* __restrict__ dstf) {
  __shared__ __attribute__((aligned(16))) unsigned short Ablk[128 * 32];
  __shared__ __attribute__((aligned(16))) unsigned short Bblk[128 * 32];
  const size_t NQ = 8192ull * 1024, NW = 1024ull * 1024;
  // XCD swizzle (grid is (8,64,gz), nwg % 8 == 0)
  int flat = ((int)blockIdx.z * 64 + blockIdx.y) * 8 + blockIdx.x;
  const int cpx = (gridDim.x * gridDim.y * gridDim.z) >> 3;
  flat = (flat & 7) * cpx + (flat >> 3);
  const int bz = flat >> 9;
  const int rem = flat & 511;
  const int by = rem >> 3, bx = rem & 7;

  const int z = bz;
  const unsigned short* A;
  const unsigned short* W;
  int m0, n0;
  if (MODE == 0 && z == 2) {
    A = Wbase + 2 * NW;      // W_v  [1024 x 1024]
    W = Abase + 2 * NQ;      // v activations [8192 x 1024]
    m0 = bx * 128;           // feature tiles (8)
    n0 = by * 128;           // token tiles (64)
  } else {
    A = Abase + (size_t)z * NQ;
    W = Wbase + (size_t)z * NW;
    m0 = by * 128;
    n0 = bx * 128;
  }
  const float* bias = biasbase + (size_t)z * 1024;
  const int tid = threadIdx.x, lane = tid & 63, w = tid >> 6;
  const int wr = (w >> 1) * 64, wc = (w & 1) * 64;
  const int llo = lane & 15, lhi = lane >> 4;
  f32x4 acc[4][4] = {};
  const unsigned short* ag = A + (size_t)(m0 + (tid >> 2)) * 1024 + (tid & 3) * 8;
  const unsigned short* wg = W + (size_t)(n0 + (tid >> 2)) * 1024 + (tid & 3) * 8;
  unsigned short* lA = &Ablk[tid * 8];
  unsigned short* lA2 = &Ablk[2048 + tid * 8];
  unsigned short* lB = &Bblk[tid * 8];
  unsigned short* lB2 = &Bblk[2048 + tid * 8];
  for (int kt = 0; kt < 32; ++kt) {
    const int ko = kt * 32;
    if (kt) __syncthreads();
    GLOAD_LDS16(ag + ko, lA);
    GLOAD_LDS16(ag + ko + 64 * 1024, lA2);
    GLOAD_LDS16(wg + ko, lB);
    GLOAD_LDS16(wg + ko + 64 * 1024, lB2);
    __syncthreads();
    bf16x8 af[4], bfr[4];
#pragma unroll
    for (int i = 0; i < 4; ++i)
      af[i] = *(const bf16x8*)&Ablk[(wr + i * 16 + llo) * 32 + lhi * 8];
#pragma unroll
    for (int i = 0; i < 4; ++i)
      bfr[i] = *(const bf16x8*)&Bblk[(wc + i * 16 + llo) * 32 + lhi * 8];
#pragma unroll
    for (int mi = 0; mi < 4; ++mi)
#pragma unroll
      for (int ni = 0; ni < 4; ++ni)
        acc[mi][ni] = MFMA16(af[mi], bfr[ni], acc[mi][ni]);
  }
  // C/D layout: col = lane&15, row = (lane>>4)*4 + r
  const float osc = (MODE == 0 && z == 0) ? 0.1803368801f : 1.0f;  // SCL for Q
#pragma unroll
  for (int mi = 0; mi < 4; ++mi) {
#pragma unroll
    for (int ni = 0; ni < 4; ++ni) {
      const int n = n0 + wc + ni * 16 + llo;
      const float bv = (MODE == 0) ? ((z == 2) ? 0.f : bias[n]) : bias[n];
#pragma unroll
      for (int r = 0; r < 4; ++r) {
        const int m = m0 + wr + mi * 16 + lhi * 4 + r;
        float val = acc[mi][ni][r] + bv;
        if (MODE == 1) {
          dstf[(size_t)m * 1024 + n] = val;
        } else if (z < 2) {
          val *= osc;
          const int b = m >> 11, s = m & 2047, h = n >> 6, d = n & 63;
          dstb[(size_t)z * NQ +
               (((size_t)(b * 16 + h) * 2048 + s) * 64 + d)] = f2bf(val);
        } else {  // z==2: m = feature (h*64+d), n = token (b*2048+s)
          val = acc[mi][ni][r] + bias[m];
          const int h = m >> 6, d = m & 63, b = n >> 11, sidx = n & 2047;
          const int t = sidx & 63;
          const int ps = (sidx & ~63) | ((t & 15) << 2) | (t >> 4);  // pi(t)
          dstb[2 * NQ + (((size_t)(b * 16 + h) * 64 + d) * 2048 + ps)] = f2bf(val);
        }
      }
    }
  }
}

// ---------------------------------------------------------------------------
// Causal flash attention, PAIRED q-tiles for perfect balance.
// Grid: 512 blocks = (8 heads/XCD-chunk) x 8 pairs x 8 xcd. Block: 4 waves.
// Block handles q-tiles (qtA=pr, qtB=15-pr): compute = 34 KV-tiles constant.
// Shared KV staging over the union range (B's range superset of A's).
// Double-buffered: STAGE(t+1) -> compute(t) -> one __syncthreads.
// No online max (Q pre-scaled to log2 domain). l via ones-fragment MFMA.
// P stored k-pi-permuted in wave-local LDS (matches V^T pi layout).
// ---------------------------------------------------------------------------
__global__ __launch_bounds__(256, 2) void attn_kernel(
    const unsigned short* __restrict__ Qp, const unsigned short* __restrict__ Kp,
    const unsigned short* __restrict__ Vtp, unsigned short* __restrict__ attn_out) {
  __shared__ __attribute__((aligned(16))) unsigned short Klds[2][64 * 64];  // swz
  __shared__ __attribute__((aligned(16))) unsigned short Vt[2][64 * 64];    // swz
  __shared__ __attribute__((aligned(16))) unsigned short Plds[4 * 32 * 72];
  // flat in [0,512): xcd = flat&7 owns bh in [xcd*8, xcd*8+8) (KV = 4MB = L2)
  const int flat = (int)blockIdx.x;
  const int xcd = flat & 7, idx = flat >> 3;
  const int bh = xcd * 8 + (idx >> 3);
  const int pr = idx & 7;
  const int tid = threadIdx.x, lane = tid & 63, w = tid >> 6;
  const int llo = lane & 15, lhi = lane >> 4;
  const int qbase[2] = {pr * 128 + w * 32, (15 - pr) * 128 + w * 32};

  // Q fragments (pre-scaled to log2 domain) for both tiles
  bf16x8 qf[2][2][2];
#pragma unroll
  for (int t = 0; t < 2; ++t)
#pragma unroll
    for (int mi = 0; mi < 2; ++mi) {
      const unsigned short* qptr =
          Qp + ((size_t)bh * 2048 + qbase[t] + mi * 16 + llo) * 64 + lhi * 8;
      qf[t][mi][0] = *(const bf16x8*)qptr;
      qf[t][mi][1] = *(const bf16x8*)(qptr + 32);
    }

  bf16x8 ones;
#pragma unroll
  for (int i = 0; i < 8; ++i) ones[i] = (short)0x3F80;

  f32x4 o[2][2][5] = {};  // [tile][mi][dblk]; dblk 4 = l (row-sum)

  const size_t kbase = (size_t)bh * (64 * 2048);
  const int r0 = tid >> 3, r1 = r0 + 32;
  const int scb = (tid & 7) * 16;
  const int kcol0 = (scb ^ ((r0 & 7) << 4)) >> 1;
  const int kcol1 = (scb ^ ((r1 & 7) << 4)) >> 1;
  const int koff0 = r0 * 64 + kcol0, koff1 = r1 * 64 + kcol1;
  const int voff0 = r0 * 2048 + kcol0, voff1 = r1 * 2048 + kcol1;
  unsigned short* pw = &Plds[w * (32 * 72)];

  const int nkt = 2 * (16 - pr);  // union range = tile B's range

#define STAGE(buf, kv0_)                                                       \
  do {                                                                         \
    GLOAD_LDS16(Kp + kbase + (size_t)(kv0_)*64 + koff0, &Klds[buf][tid * 8]);  \
    GLOAD_LDS16(Kp + kbase + (size_t)(kv0_)*64 + koff1,                        \
                &Klds[buf][2048 + tid * 8]);                                   \
    GLOAD_LDS16(Vtp + kbase + (kv0_) + voff0, &Vt[buf][tid * 8]);              \
    GLOAD_LDS16(Vtp + kbase + (kv0_) + voff1, &Vt[buf][2048 + tid * 8]);       \
  } while (0)

  STAGE(0, 0);
  __syncthreads();

  for (int kt = 0; kt < nkt; ++kt) {
    const int kv0 = kt * 64;
    const int cb = kt & 1;
    if (kt + 1 < nkt) STAGE(cb ^ 1, kv0 + 64);

#pragma unroll
    for (int t = 0; t < 2; ++t) {
      const int qb = qbase[t];
      if (kv0 <= qb + 31) {  // wave-uniform causal range check
        // ---- S = Q K^T
        f32x4 s[2][4] = {};
        __builtin_amdgcn_s_setprio(1);
#pragma unroll
        for (int b4 = 0; b4 < 4; ++b4) {
          const int row = b4 * 16 + llo;
          const int sw = (row & 7) << 3;
          const bf16x8 k0 =
              *(const bf16x8*)&Klds[cb][row * 64 + ((lhi * 8) ^ sw)];
          const bf16x8 k1 =
              *(const bf16x8*)&Klds[cb][row * 64 + ((32 + lhi * 8) ^ sw)];
          s[0][b4] = MFMA16(qf[t][0][0], k0, s[0][b4]);
          s[0][b4] = MFMA16(qf[t][0][1], k1, s[0][b4]);
          s[1][b4] = MFMA16(qf[t][1][0], k0, s[1][b4]);
          s[1][b4] = MFMA16(qf[t][1][1], k1, s[1][b4]);
        }
        __builtin_amdgcn_s_setprio(0);

        // ---- P = exp2(S) (+mask on diagonal tiles), packed pi-store
        const bool needm = (kv0 + 63 > qb);
#pragma unroll
        for (int mi = 0; mi < 2; ++mi) {
#pragma unroll
          for (int r = 0; r < 4; ++r) {
            float sv0 = s[mi][0][r], sv1 = s[mi][1][r];
            float sv2 = s[mi][2][r], sv3 = s[mi][3][r];
            if (needm) {
              const int qrow = qb + mi * 16 + lhi * 4 + r;
              if (kv0 + llo > qrow) sv0 = -1e9f;
              if (kv0 + 16 + llo > qrow) sv1 = -1e9f;
              if (kv0 + 32 + llo > qrow) sv2 = -1e9f;
              if (kv0 + 48 + llo > qrow) sv3 = -1e9f;
            }
            const float p0 = exp2f(sv0), p1 = exp2f(sv1);
            const float p2 = exp2f(sv2), p3 = exp2f(sv3);
            const int prow = mi * 16 + lhi * 4 + r;
            *(uint2*)&pw[prow * 72 + llo * 4] =
                make_uint2(pk2(p0, p1), pk2(p2, p3));
          }
        }

        // ---- O += P V^T; l via ones B-fragment
        bf16x8 pa[2][2];
#pragma unroll
        for (int mi = 0; mi < 2; ++mi) {
          pa[mi][0] = *(const bf16x8*)&pw[(mi * 16 + llo) * 72 + lhi * 8];
          pa[mi][1] = *(const bf16x8*)&pw[(mi * 16 + llo) * 72 + 32 + lhi * 8];
        }
        __builtin_amdgcn_s_setprio(1);
#pragma unroll
        for (int dblk = 0; dblk < 4; ++dblk) {
          const int row = dblk * 16 + llo;
          const int sw = (row & 7) << 3;
          const bf16x8 v0 =
              *(const bf16x8*)&Vt[cb][row * 64 + ((lhi * 8) ^ sw)];
          const bf16x8 v1 =
              *(const bf16x8*)&Vt[cb][row * 64 + ((32 + lhi * 8) ^ sw)];
          o[t][0][dblk] = MFMA16(pa[0][0], v0, o[t][0][dblk]);
          o[t][0][dblk] = MFMA16(pa[0][1], v1, o[t][0][dblk]);
          o[t][1][dblk] = MFMA16(pa[1][0], v0, o[t][1][dblk]);
          o[t][1][dblk] = MFMA16(pa[1][1], v1, o[t][1][dblk]);
        }
        o[t][0][4] = MFMA16(pa[0][0], ones, o[t][0][4]);
        o[t][0][4] = MFMA16(pa[0][1], ones, o[t][0][4]);
        o[t][1][4] = MFMA16(pa[1][0], ones, o[t][1][4]);
        o[t][1][4] = MFMA16(pa[1][1], ones, o[t][1][4]);
        __builtin_amdgcn_s_setprio(0);
      }
    }

    __syncthreads();  // drains vmcnt: STAGE(t+1) had compute(t) to land
  }
#undef STAGE

  // ---- epilogue: O/l for both tiles, scatter to (B,S,D) bf16
  const int b = bh >> 4, h = bh & 15;
#pragma unroll
  for (int t = 0; t < 2; ++t) {
#pragma unroll
    for (int mi = 0; mi < 2; ++mi) {
#pragma unroll
      for (int r = 0; r < 4; ++r) {
        const float inv = 1.0f / o[t][mi][4][r];
        const int qrow = qbase[t] + mi * 16 + lhi * 4 + r;
        const size_t base = ((size_t)b * 2048 + qrow) * 1024 + h * 64;
#pragma unroll
        for (int dblk = 0; dblk < 4; ++dblk)
          attn_out[base + dblk * 16 + llo] = f2bf(o[t][mi][dblk][r] * inv);
      }
    }
  }
}

// ---------------------------------------------------------------------------
extern "C" void kernel_launch(void* const* d_in, const int* in_sizes, int n_in,
                              void* d_out, int out_size, void* d_ws,
                              size_t ws_size, hipStream_t stream) {
  const float* q = (const float*)d_in[0];
  const float* k = (const float*)d_in[1];
  const float* v = (const float*)d_in[2];
  const float* wq_w = (const float*)d_in[3];
  const float* wq_b = (const float*)d_in[4];
  const float* wk_w = (const float*)d_in[5];
  const float* wk_b = (const float*)d_in[6];
  const float* wv_w = (const float*)d_in[7];
  const float* wv_b = (const float*)d_in[8];
  const float* dense_w = (const float*)d_in[9];
  const float* dense_b = (const float*)d_in[10];
  float* out = (float*)d_out;

  char* ws = (char*)d_ws;
  const size_t MB = 1024ull * 1024;
  unsigned short* qkv_bf = (unsigned short*)(ws);
  unsigned short* w_bf = (unsigned short*)(ws + 48 * MB);
  float* bias_pack = (float*)(ws + 56 * MB);
  unsigned short* qkvp = (unsigned short*)(ws + 57 * MB);
  unsigned short* attn_o = (unsigned short*)(ws + 105 * MB);
  const size_t PEL = 8192ull * 1024;

  convert_kernel<<<dim3(2048), dim3(256), 0, stream>>>(
      q, k, v, wq_w, wk_w, wv_w, dense_w, wq_b, wk_b, wv_b, qkv_bf, bias_pack);

  // Q (scaled), K -> (B,H,S,64); V^T pi-permuted -> (B,H,64,S). One dispatch.
  gemm_kernel<0><<<dim3(8, 64, 3), dim3(256), 0, stream>>>(
      qkv_bf, w_bf, bias_pack, qkvp, nullptr);

  attn_kernel<<<dim3(512), dim3(256), 0, stream>>>(
      qkvp, qkvp + PEL, qkvp + 2 * PEL, attn_o);

  gemm_kernel<1><<<dim3(8, 64, 1), dim3(256), 0, stream>>>(
      attn_o, w_bf + 3ull * 1024 * 1024, dense_b, nullptr, out);
}

// Round 9
// 200.049 us; speedup vs baseline: 1.4719x; 1.0502x over previous
//
#include <hip/hip_runtime.h>
#include <hip/hip_bf16.h>

// B=4, S=2048, D=1024, H=16, DEPTH=64. Causal MHA, fp32 in/out, bf16 MFMA.

typedef __attribute__((ext_vector_type(8))) short bf16x8;
typedef __attribute__((ext_vector_type(4))) float f32x4;
typedef __attribute__((ext_vector_type(8))) unsigned short u16x8;

#define MFMA16(a, b, c) __builtin_amdgcn_mfma_f32_16x16x32_bf16(a, b, c, 0, 0, 0)

#define GLOAD_LDS16(gp, lp)                                                    \
  __builtin_amdgcn_global_load_lds(                                            \
      (const __attribute__((address_space(1))) void*)(gp),                     \
      (__attribute__((address_space(3))) void*)(lp), 16, 0, 0)

__device__ __forceinline__ unsigned short f2bf(float f) {
  union { float f; unsigned u; } x; x.f = f;
  unsigned u = x.u;
  return (unsigned short)((u + 0x7fffu + ((u >> 16) & 1u)) >> 16);
}

__device__ __forceinline__ unsigned pk2(float a, float b) {
  union { __hip_bfloat162 h; unsigned u; } cv;
  cv.h = __float22bfloat162_rn(float2{a, b});
  return cv.u;
}

// ---------------------------------------------------------------------------
// fp32 -> bf16 convert for q,k,v (3x8M) + weights (4x1M); packs qkv biases.
// ---------------------------------------------------------------------------
__global__ __launch_bounds__(256) void convert_kernel(
    const float* __restrict__ q, const float* __restrict__ k,
    const float* __restrict__ v, const float* __restrict__ wq,
    const float* __restrict__ wk, const float* __restrict__ wv,
    const float* __restrict__ wd, const float* __restrict__ bq,
    const float* __restrict__ bk, const float* __restrict__ bv,
    unsigned short* __restrict__ dst, float* __restrict__ bias_pack) {
  const size_t tid0 = (size_t)blockIdx.x * blockDim.x + threadIdx.x;
  const size_t nthreads = (size_t)gridDim.x * blockDim.x;
  if (tid0 < 3072) {
    bias_pack[tid0] = tid0 < 1024 ? bq[tid0]
                     : (tid0 < 2048 ? bk[tid0 - 1024] : bv[tid0 - 2048]);
  }
  const size_t NQ = 8192ull * 1024;
  const size_t NW = 1024ull * 1024;
  const size_t total_chunks = (3 * NQ + 4 * NW) / 8;
  for (size_t c = tid0; c < total_chunks; c += nthreads) {
    const size_t e = c * 8;
    const float* src;
    if (e < NQ) src = q + e;
    else if (e < 2 * NQ) src = k + (e - NQ);
    else if (e < 3 * NQ) src = v + (e - 2 * NQ);
    else {
      const size_t we = e - 3 * NQ;
      if (we < NW) src = wq + we;
      else if (we < 2 * NW) src = wk + (we - NW);
      else if (we < 3 * NW) src = wv + (we - 2 * NW);
      else src = wd + (we - 3 * NW);
    }
    f32x4 a = *(const f32x4*)(src);
    f32x4 b = *(const f32x4*)(src + 4);
    u16x8 o;
    o[0] = f2bf(a[0]); o[1] = f2bf(a[1]); o[2] = f2bf(a[2]); o[3] = f2bf(a[3]);
    o[4] = f2bf(b[0]); o[5] = f2bf(b[1]); o[6] = f2bf(b[2]); o[7] = f2bf(b[3]);
    *(u16x8*)(dst + e) = o;
  }
}

// ---------------------------------------------------------------------------
// 8-phase-style pipelined GEMM: C = A[.,1024] @ W[.,1024]^T + bias.
// BM=128, BN=256, BK=64, 512 threads = 8 waves (2M x 4N), per-wave 64x64.
// 3 LDS buffers, 2-tiles-ahead prefetch, counted vmcnt (9 steady / 6 / 0),
// per-K-tile: 2 setprio'd 16-MFMA phases, 3 barriers. XOR col-swizzle
// (col16 ^= row&7) applied on staging source AND ds_read (bank-conflict-free).
// MODE 0: z in {0,1}: Q (log2-scaled) / K -> head layout (B,H,S,64).
// MODE 2: V role-swapped (A=W_v, W=v-act) -> V^T (B,H,64,S) pi-permuted.
// MODE 1: dense -> fp32 row-major.
// ---------------------------------------------------------------------------
template <int MODE>
__global__ __launch_bounds__(512, 2) void gemm8_kernel(
    const unsigned short* __restrict__ Abase,
    const unsigned short* __restrict__ Wbase,
    const float* __restrict__ biasbase, unsigned short* __restrict__ dstb,
    float* __restrict__ dstf) {
  __shared__ __attribute__((aligned(16))) unsigned short Ablk[3][128 * 64];
  __shared__ __attribute__((aligned(16))) unsigned short Bblk[3][256 * 64];
  const size_t NQ = 8192ull * 1024, NW = 1024ull * 1024;
  // XCD-chunked swizzle (total blocks % 8 == 0)
  const int nx = gridDim.x, ny = gridDim.y;
  const int tot = nx * ny * (int)gridDim.z;
  int flat = ((int)blockIdx.z * ny + blockIdx.y) * nx + blockIdx.x;
  flat = (flat & 7) * (tot >> 3) + (flat >> 3);
  const int bx = flat % nx;
  const int tmp = flat / nx;
  const int by = tmp % ny;
  const int z = tmp / ny;

  const unsigned short* A;
  const unsigned short* W;
  if (MODE == 0) { A = Abase + (size_t)z * NQ; W = Wbase + (size_t)z * NW; }
  else if (MODE == 2) { A = Wbase + 2 * NW; W = Abase + 2 * NQ; }
  else { A = Abase; W = Wbase; }
  const int m0 = by * 128, n0 = bx * 256;

  const int tid = threadIdx.x, lane = tid & 63, w = tid >> 6;
  const int wm = w >> 2, wn = w & 3;
  const int llo = lane & 15, lhi = lane >> 4;

  // Staging: chunk c -> LDS byte c*16 (linear); row = c>>3, src col16 =
  // (c&7) ^ (row&7) [swizzle involution]. Thread stages A chunks {tid,
  // tid+512}, B chunks {tid, tid+512, tid+1024, tid+1536}.
  int srcA[2], srcB[4];
#pragma unroll
  for (int j = 0; j < 4; ++j) {
    const int c = tid + j * 512;
    const int off = (c >> 3) * 1024 + ((((c & 7) ^ ((c >> 3) & 7))) << 3);
    if (j < 2) srcA[j] = off;
    srcB[j] = off;
  }
  const unsigned short* Ag = A + (size_t)m0 * 1024;
  const unsigned short* Wg = W + (size_t)n0 * 1024;

#define STA(bi, kt_, j)                                                        \
  GLOAD_LDS16(Ag + srcA[j] + (kt_) * 64,                                       \
              (unsigned short*)Ablk[bi] + (tid + (j) * 512) * 8)
#define STB(bi, kt_, j)                                                        \
  GLOAD_LDS16(Wg + srcB[j] + (kt_) * 64,                                       \
              (unsigned short*)Bblk[bi] + (tid + (j) * 512) * 8)

  f32x4 acc[4][4] = {};
  const int cswz0 = ((lhi ^ (llo & 7)) << 3);        // k-half 0 col (elems)
  const int cswz1 = (((4 + lhi) ^ (llo & 7)) << 3);  // k-half 1

  // prologue: tiles 0 and 1 (12 loads/thread outstanding)
  STA(0, 0, 0); STA(0, 0, 1);
  STB(0, 0, 0); STB(0, 0, 1); STB(0, 0, 2); STB(0, 0, 3);
  STA(1, 1, 0); STA(1, 1, 1);
  STB(1, 1, 0); STB(1, 1, 1); STB(1, 1, 2); STB(1, 1, 3);

#pragma unroll
  for (int kt = 0; kt < 16; ++kt) {
    const int cb = kt % 3, nb = (kt + 2) % 3;
    __builtin_amdgcn_s_barrier();  // (1) all waves done reading buf nb
    __builtin_amdgcn_sched_barrier(0);
    if (kt + 2 < 16) { STA(nb, kt + 2, 0); STA(nb, kt + 2, 1); STB(nb, kt + 2, 0); }
    if (kt <= 13) asm volatile("s_waitcnt vmcnt(9)" ::: "memory");
    else if (kt == 14) asm volatile("s_waitcnt vmcnt(6)" ::: "memory");
    else asm volatile("s_waitcnt vmcnt(0)" ::: "memory");
    __builtin_amdgcn_s_barrier();  // (2) tile kt fully in LDS
    __builtin_amdgcn_sched_barrier(0);

    // ---- phase A: all A-frags + B-frags n0,n1; 16 MFMA
    bf16x8 af[4][2], bf01[2][2];
#pragma unroll
    for (int mi = 0; mi < 4; ++mi) {
      const int ar = (wm * 64 + mi * 16 + llo) * 64;
      af[mi][0] = *(const bf16x8*)&Ablk[cb][ar + cswz0];
      af[mi][1] = *(const bf16x8*)&Ablk[cb][ar + cswz1];
    }
#pragma unroll
    for (int ni = 0; ni < 2; ++ni) {
      const int br = (wn * 64 + ni * 16 + llo) * 64;
      bf01[ni][0] = *(const bf16x8*)&Bblk[cb][br + cswz0];
      bf01[ni][1] = *(const bf16x8*)&Bblk[cb][br + cswz1];
    }
    __builtin_amdgcn_s_setprio(1);
#pragma unroll
    for (int mi = 0; mi < 4; ++mi)
#pragma unroll
      for (int ni = 0; ni < 2; ++ni) {
        acc[mi][ni] = MFMA16(af[mi][0], bf01[ni][0], acc[mi][ni]);
        acc[mi][ni] = MFMA16(af[mi][1], bf01[ni][1], acc[mi][ni]);
      }
    __builtin_amdgcn_s_setprio(0);
    __builtin_amdgcn_s_barrier();  // (3) phase boundary
    __builtin_amdgcn_sched_barrier(0);

    // ---- phase B: B-frags n2,n3; 16 MFMA
    if (kt + 2 < 16) { STB(nb, kt + 2, 1); STB(nb, kt + 2, 2); STB(nb, kt + 2, 3); }
    bf16x8 bf23[2][2];
#pragma unroll
    for (int ni = 0; ni < 2; ++ni) {
      const int br = (wn * 64 + (ni + 2) * 16 + llo) * 64;
      bf23[ni][0] = *(const bf16x8*)&Bblk[cb][br + cswz0];
      bf23[ni][1] = *(const bf16x8*)&Bblk[cb][br + cswz1];
    }
    __builtin_amdgcn_s_setprio(1);
#pragma unroll
    for (int mi = 0; mi < 4; ++mi)
#pragma unroll
      for (int ni = 0; ni < 2; ++ni) {
        acc[mi][ni + 2] = MFMA16(af[mi][0], bf23[ni][0], acc[mi][ni + 2]);
        acc[mi][ni + 2] = MFMA16(af[mi][1], bf23[ni][1], acc[mi][ni + 2]);
      }
    __builtin_amdgcn_s_setprio(0);
  }
#undef STA
#undef STB

  // ---- epilogue. C/D layout: col = lane&15, row = (lane>>4)*4 + r
  const float osc = (MODE == 0 && z == 0) ? 0.1803368801f : 1.0f;
  const float* bias = (MODE == 0) ? biasbase + (size_t)z * 1024
                     : (MODE == 2) ? biasbase + 2048 : biasbase;
#pragma unroll
  for (int mi = 0; mi < 4; ++mi) {
#pragma unroll
    for (int ni = 0; ni < 4; ++ni) {
      const int n = n0 + wn * 64 + ni * 16 + llo;
      const int mbase = m0 + wm * 64 + mi * 16 + lhi * 4;
#pragma unroll
      for (int r = 0; r < 4; ++r) {
        const int m = mbase + r;
        if (MODE == 1) {
          dstf[(size_t)m * 1024 + n] = acc[mi][ni][r] + bias[n];
        } else if (MODE == 0) {
          const float val = (acc[mi][ni][r] + bias[n]) * osc;
          const int b = m >> 11, s = m & 2047, h = n >> 6, d = n & 63;
          dstb[(size_t)z * NQ + (((size_t)(b * 16 + h) * 2048 + s) * 64 + d)] =
              f2bf(val);
        } else {  // MODE 2: m = feature (h*64+d), n = token (b*2048+s)
          const float val = acc[mi][ni][r] + bias[m];
          const int h = m >> 6, d = m & 63, b = n >> 11, sidx = n & 2047;
          const int t = sidx & 63;
          const int ps = (sidx & ~63) | ((t & 15) << 2) | (t >> 4);  // pi(t)
          dstb[2 * NQ + (((size_t)(b * 16 + h) * 64 + d) * 2048 + ps)] =
              f2bf(val);
        }
      }
    }
  }
}

// ---------------------------------------------------------------------------
// Causal flash attention, PAIRED q-tiles (R8 best). Grid 512, 4 waves.
// ---------------------------------------------------------------------------
__global__ __launch_bounds__(256, 2) void attn_kernel(
    const unsigned short* __restrict__ Qp, const unsigned short* __restrict__ Kp,
    const unsigned short* __restrict__ Vtp, unsigned short* __restrict__ attn_out) {
  __shared__ __attribute__((aligned(16))) unsigned short Klds[2][64 * 64];  // swz
  __shared__ __attribute__((aligned(16))) unsigned short Vt[2][64 * 64];    // swz
  __shared__ __attribute__((aligned(16))) unsigned short Plds[4 * 32 * 72];
  const int flat = (int)blockIdx.x;
  const int xcd = flat & 7, idx = flat >> 3;
  const int bh = xcd * 8 + (idx >> 3);
  const int pr = idx & 7;
  const int tid = threadIdx.x, lane = tid & 63, w = tid >> 6;
  const int llo = lane & 15, lhi = lane >> 4;
  const int qbase[2] = {pr * 128 + w * 32, (15 - pr) * 128 + w * 32};

  bf16x8 qf[2][2][2];
#pragma unroll
  for (int t = 0; t < 2; ++t)
#pragma unroll
    for (int mi = 0; mi < 2; ++mi) {
      const unsigned short* qptr =
          Qp + ((size_t)bh * 2048 + qbase[t] + mi * 16 + llo) * 64 + lhi * 8;
      qf[t][mi][0] = *(const bf16x8*)qptr;
      qf[t][mi][1] = *(const bf16x8*)(qptr + 32);
    }

  bf16x8 ones;
#pragma unroll
  for (int i = 0; i < 8; ++i) ones[i] = (short)0x3F80;

  f32x4 o[2][2][5] = {};  // [tile][mi][dblk]; dblk 4 = l

  const size_t kbase = (size_t)bh * (64 * 2048);
  const int r0 = tid >> 3, r1 = r0 + 32;
  const int scb = (tid & 7) * 16;
  const int kcol0 = (scb ^ ((r0 & 7) << 4)) >> 1;
  const int kcol1 = (scb ^ ((r1 & 7) << 4)) >> 1;
  const int koff0 = r0 * 64 + kcol0, koff1 = r1 * 64 + kcol1;
  const int voff0 = r0 * 2048 + kcol0, voff1 = r1 * 2048 + kcol1;
  unsigned short* pw = &Plds[w * (32 * 72)];

  const int nkt = 2 * (16 - pr);

#define STAGE(buf, kv0_)                                                       \
  do {                                                                         \
    GLOAD_LDS16(Kp + kbase + (size_t)(kv0_)*64 + koff0, &Klds[buf][tid * 8]);  \
    GLOAD_LDS16(Kp + kbase + (size_t)(kv0_)*64 + koff1,                        \
                &Klds[buf][2048 + tid * 8]);                                   \
    GLOAD_LDS16(Vtp + kbase + (kv0_) + voff0, &Vt[buf][tid * 8]);              \
    GLOAD_LDS16(Vtp + kbase + (kv0_) + voff1, &Vt[buf][2048 + tid * 8]);       \
  } while (0)

  STAGE(0, 0);
  __syncthreads();

  for (int kt = 0; kt < nkt; ++kt) {
    const int kv0 = kt * 64;
    const int cb = kt & 1;
    if (kt + 1 < nkt) STAGE(cb ^ 1, kv0 + 64);

#pragma unroll
    for (int t = 0; t < 2; ++t) {
      const int qb = qbase[t];
      if (kv0 <= qb + 31) {
        f32x4 s[2][4] = {};
        __builtin_amdgcn_s_setprio(1);
#pragma unroll
        for (int b4 = 0; b4 < 4; ++b4) {
          const int row = b4 * 16 + llo;
          const int sw = (row & 7) << 3;
          const bf16x8 k0 =
              *(const bf16x8*)&Klds[cb][row * 64 + ((lhi * 8) ^ sw)];
          const bf16x8 k1 =
              *(const bf16x8*)&Klds[cb][row * 64 + ((32 + lhi * 8) ^ sw)];
          s[0][b4] = MFMA16(qf[t][0][0], k0, s[0][b4]);
          s[0][b4] = MFMA16(qf[t][0][1], k1, s[0][b4]);
          s[1][b4] = MFMA16(qf[t][1][0], k0, s[1][b4]);
          s[1][b4] = MFMA16(qf[t][1][1], k1, s[1][b4]);
        }
        __builtin_amdgcn_s_setprio(0);

        const bool needm = (kv0 + 63 > qb);
#pragma unroll
        for (int mi = 0; mi < 2; ++mi) {
#pragma unroll
          for (int r = 0; r < 4; ++r) {
            float sv0 = s[mi][0][r], sv1 = s[mi][1][r];
            float sv2 = s[mi][2][r], sv3 = s[mi][3][r];
            if (needm) {
              const int qrow = qb + mi * 16 + lhi * 4 + r;
              if (kv0 + llo > qrow) sv0 = -1e9f;
              if (kv0 + 16 + llo > qrow) sv1 = -1e9f;
              if (kv0 + 32 + llo > qrow) sv2 = -1e9f;
              if (kv0 + 48 + llo > qrow) sv3 = -1e9f;
            }
            const float p0 = exp2f(sv0), p1 = exp2f(sv1);
            const float p2 = exp2f(sv2), p3 = exp2f(sv3);
            const int prow = mi * 16 + lhi * 4 + r;
            *(uint2*)&pw[prow * 72 + llo * 4] =
                make_uint2(pk2(p0, p1), pk2(p2, p3));
          }
        }

        bf16x8 pa[2][2];
#pragma unroll
        for (int mi = 0; mi < 2; ++mi) {
          pa[mi][0] = *(const bf16x8*)&pw[(mi * 16 + llo) * 72 + lhi * 8];
          pa[mi][1] = *(const bf16x8*)&pw[(mi * 16 + llo) * 72 + 32 + lhi * 8];
        }
        __builtin_amdgcn_s_setprio(1);
#pragma unroll
        for (int dblk = 0; dblk < 4; ++dblk) {
          const int row = dblk * 16 + llo;
          const int sw = (row & 7) << 3;
          const bf16x8 v0 =
              *(const bf16x8*)&Vt[cb][row * 64 + ((lhi * 8) ^ sw)];
          const bf16x8 v1 =
              *(const bf16x8*)&Vt[cb][row * 64 + ((32 + lhi * 8) ^ sw)];
          o[t][0][dblk] = MFMA16(pa[0][0], v0, o[t][0][dblk]);
          o[t][0][dblk] = MFMA16(pa[0][1], v1, o[t][0][dblk]);
          o[t][1][dblk] = MFMA16(pa[1][0], v0, o[t][1][dblk]);
          o[t][1][dblk] = MFMA16(pa[1][1], v1, o[t][1][dblk]);
        }
        o[t][0][4] = MFMA16(pa[0][0], ones, o[t][0][4]);
        o[t][0][4] = MFMA16(pa[0][1], ones, o[t][0][4]);
        o[t][1][4] = MFMA16(pa[1][0], ones, o[t][1][4]);
        o[t][1][4] = MFMA16(pa[1][1], ones, o[t][1][4]);
        __builtin_amdgcn_s_setprio(0);
      }
    }

    __syncthreads();
  }
#undef STAGE

  const int b = bh >> 4, h = bh & 15;
#pragma unroll
  for (int t = 0; t < 2; ++t) {
#pragma unroll
    for (int mi = 0; mi < 2; ++mi) {
#pragma unroll
      for (int r = 0; r < 4; ++r) {
        const float inv = 1.0f / o[t][mi][4][r];
        const int qrow = qbase[t] + mi * 16 + lhi * 4 + r;
        const size_t base = ((size_t)b * 2048 + qrow) * 1024 + h * 64;
#pragma unroll
        for (int dblk = 0; dblk < 4; ++dblk)
          attn_out[base + dblk * 16 + llo] = f2bf(o[t][mi][dblk][r] * inv);
      }
    }
  }
}

// ---------------------------------------------------------------------------
extern "C" void kernel_launch(void* const* d_in, const int* in_sizes, int n_in,
                              void* d_out, int out_size, void* d_ws,
                              size_t ws_size, hipStream_t stream) {
  const float* q = (const float*)d_in[0];
  const float* k = (const float*)d_in[1];
  const float* v = (const float*)d_in[2];
  const float* wq_w = (const float*)d_in[3];
  const float* wq_b = (const float*)d_in[4];
  const float* wk_w = (const float*)d_in[5];
  const float* wk_b = (const float*)d_in[6];
  const float* wv_w = (const float*)d_in[7];
  const float* wv_b = (const float*)d_in[8];
  const float* dense_w = (const float*)d_in[9];
  const float* dense_b = (const float*)d_in[10];
  float* out = (float*)d_out;

  char* ws = (char*)d_ws;
  const size_t MB = 1024ull * 1024;
  unsigned short* qkv_bf = (unsigned short*)(ws);
  unsigned short* w_bf = (unsigned short*)(ws + 48 * MB);
  float* bias_pack = (float*)(ws + 56 * MB);
  unsigned short* qkvp = (unsigned short*)(ws + 57 * MB);
  unsigned short* attn_o = (unsigned short*)(ws + 105 * MB);
  const size_t PEL = 8192ull * 1024;

  convert_kernel<<<dim3(2048), dim3(256), 0, stream>>>(
      q, k, v, wq_w, wk_w, wv_w, dense_w, wq_b, wk_b, wv_b, qkv_bf, bias_pack);

  // Q (scaled), K -> (B,H,S,64): 512 blocks = 2 exact CU-rounds
  gemm8_kernel<0><<<dim3(4, 64, 2), dim3(512), 0, stream>>>(
      qkv_bf, w_bf, bias_pack, qkvp, nullptr);

  // V role-swapped -> V^T (B,H,64,S) pi-permuted: 256 blocks = 1 round
  gemm8_kernel<2><<<dim3(32, 8, 1), dim3(512), 0, stream>>>(
      qkv_bf, w_bf, bias_pack, qkvp, nullptr);

  attn_kernel<<<dim3(512), dim3(256), 0, stream>>>(
      qkvp, qkvp + PEL, qkvp + 2 * PEL, attn_o);

  // dense: 256 blocks = 1 round
  gemm8_kernel<1><<<dim3(4, 64, 1), dim3(512), 0, stream>>>(
      attn_o, w_bf + 3ull * 1024 * 1024, dense_b, nullptr, out);
}